// Round 4
// baseline (258.591 us; speedup 1.0000x reference)
//
#include <hip/hip_runtime.h>

#define BATCH 8
#define NBOX 2000
#define NCLS 81
#define NPAD 2048
#define MAX_OUT 300
#define SCORE_T 0.05f
#define IOU_T 0.5f
#define NMS_THREADS 256

// ---------------- prep: softmax fg score/cls + box regression ----------------
__global__ void prep_kernel(const float* __restrict__ deltas,
                            const float* __restrict__ logits,
                            const float* __restrict__ proposals,
                            float4* __restrict__ boxes_out,
                            float* __restrict__ scores_out) {
    int bn = blockIdx.x * blockDim.x + threadIdx.x;
    if (bn >= BATCH * NBOX) return;

    const float* l = logits + (long)bn * NCLS;

    float M = l[0];
    #pragma unroll 4
    for (int c = 1; c < NCLS; ++c) M = fmaxf(M, l[c]);

    float S = 0.0f;
    float bl = -3.0e38f; int bc = 1;
    #pragma unroll 4
    for (int c = 0; c < NCLS; ++c) {
        float v = l[c];
        S += expf(v - M);
        if (c >= 1 && v > bl) { bl = v; bc = c; }
    }
    float score = expf(bl - M) / S;

    const float* p = proposals + (long)bn * 5;
    float y1 = p[0], x1 = p[1], y2 = p[2], x2 = p[3];
    float h = y2 - y1, w = x2 - x1;
    float cy = (y2 + y1) * 0.5f, cx = (x2 + x1) * 0.5f;

    const float* d = deltas + ((long)bn * NCLS + bc) * 4;
    float d0 = d[0] * 0.1f, d1 = d[1] * 0.1f, d2 = d[2] * 0.2f, d3 = d[3] * 0.2f;

    cy = cy + d0 * h;
    cx = cx + d1 * w;
    h = h * expf(d2);
    w = w * expf(d3);

    boxes_out[bn] = make_float4(cy - h * 0.5f, cx - w * 0.5f,
                                cy + h * 0.5f, cx + w * 0.5f);
    scores_out[bn] = score;
}

// ------- NMS: 256-thread bitonic sort + wave-0 walk with pairwise-mask resolve -------
__global__ __launch_bounds__(NMS_THREADS) void nms_kernel(
        const float4* __restrict__ boxes,
        const float* __restrict__ scores,
        float4* __restrict__ kbox,
        float* __restrict__ kscore,
        int* __restrict__ kidx,
        int* __restrict__ kcount) {
    int b = blockIdx.x;
    int tid = threadIdx.x;

    __shared__ unsigned long long s_key[NPAD];   // 16 KB
    __shared__ float4 s_bx[NPAD];                // 32 KB
    __shared__ float4 s_kbox[MAX_OUT];
    __shared__ float  s_kar[MAX_OUT];
    __shared__ float  s_ksc[MAX_OUT];
    __shared__ int    s_kidx[MAX_OUT];
    __shared__ int    s_L;
    __shared__ int    s_kcount;

    if (tid == 0) { s_L = 0; s_kcount = 0; }

    // keys: hi32 = score bits (positive floats -> monotone), lo32 = ~index (stable ties)
    for (int r = tid; r < NPAD; r += NMS_THREADS) {
        unsigned long long key = 0ull;
        if (r < NBOX) {
            float s = scores[b * NBOX + r];
            key = ((unsigned long long)__float_as_uint(s) << 32) |
                  (unsigned long long)(0xFFFFFFFFu - (unsigned)r);
        }
        s_key[r] = key;
    }
    __syncthreads();

    // bitonic sort, descending (4-wave barriers)
    for (int k = 2; k <= NPAD; k <<= 1) {
        for (int j = k >> 1; j > 0; j >>= 1) {
            for (int i = tid; i < NPAD; i += NMS_THREADS) {
                int l = i ^ j;
                if (l > i) {
                    unsigned long long a = s_key[i], c = s_key[l];
                    bool up = ((i & k) == 0);
                    if ((a < c) == up) { s_key[i] = c; s_key[l] = a; }
                }
            }
            __syncthreads();
        }
    }

    // gather boxes into sorted order; detect alive-prefix length L
    for (int r = tid; r < NPAD; r += NMS_THREADS) {
        unsigned long long key = s_key[r];
        unsigned int fb = (unsigned int)(key >> 32);
        float sc = __uint_as_float(fb);
        float4 bx = make_float4(0.f, 0.f, 0.f, 0.f);
        if (fb) {
            int orig = (int)(0xFFFFFFFFu - (unsigned int)key);
            bx = boxes[b * NBOX + orig];
        }
        s_bx[r] = bx;
        float scn = 0.0f;
        if (r + 1 < NPAD) scn = __uint_as_float((unsigned int)(s_key[r + 1] >> 32));
        if (sc > SCORE_T && !(scn > SCORE_T)) s_L = r + 1;
    }
    __syncthreads();

    // wave-0 greedy walk, 64 candidates per chunk
    if (tid < 64) {
        int lane = tid;
        int L = s_L;
        int kept = 0;
        int nblk = (L + 63) >> 6;
        for (int blk = 0; blk < nblk && kept < MAX_OUT; ++blk) {
            int base = blk << 6;
            int r = base + lane;
            bool valid = (r < L);
            float4 bx = s_bx[r];
            float area = (bx.z - bx.x) * (bx.w - bx.y);
            unsigned long long key = s_key[r];
            float myscore = __uint_as_float((unsigned int)(key >> 32));
            int myorig = (int)(0xFFFFFFFFu - (unsigned int)key);

            // check against previously-kept boxes (pipelined LDS broadcast reads)
            bool sup = false;
            #pragma unroll 4
            for (int k = 0; k < kept; ++k) {
                float4 kb = s_kbox[k];
                float ka = s_kar[k];
                float yy1 = fmaxf(bx.x, kb.x), xx1 = fmaxf(bx.y, kb.y);
                float yy2 = fminf(bx.z, kb.z), xx2 = fminf(bx.w, kb.w);
                float inter = fmaxf(yy2 - yy1, 0.f) * fmaxf(xx2 - xx1, 0.f);
                float iou = inter / (area + ka - inter + 1e-8f);
                sup = sup || (iou > IOU_T);
            }
            unsigned long long live = __ballot(valid && !sup);
            if (!live) continue;

            // pairwise suppression mask within chunk (IoU symmetric: row == col)
            unsigned long long m = 0;
            for (int i = 0; i < 64; ++i) {
                float4 ob = s_bx[base + i];
                float oa = (ob.z - ob.x) * (ob.w - ob.y);
                float yy1 = fmaxf(bx.x, ob.x), xx1 = fmaxf(bx.y, ob.y);
                float yy2 = fminf(bx.z, ob.z), xx2 = fminf(bx.w, ob.w);
                float inter = fmaxf(yy2 - yy1, 0.f) * fmaxf(xx2 - xx1, 0.f);
                float iou = inter / (area + oa - inter + 1e-8f);
                if (iou > IOU_T) m |= (1ull << i);
            }

            // scalar greedy resolve: ctz + readlane (zero-extend! readlane returns int)
            unsigned int mlo = (unsigned int)m;
            unsigned int mhi = (unsigned int)(m >> 32);
            while (live && kept < MAX_OUT) {
                int w = (int)__builtin_ctzll(live);
                unsigned int clo = (unsigned int)__builtin_amdgcn_readlane((int)mlo, w);
                unsigned int chi = (unsigned int)__builtin_amdgcn_readlane((int)mhi, w);
                unsigned long long colw =
                    ((unsigned long long)chi << 32) | (unsigned long long)clo;
                if (lane == w) {
                    s_kbox[kept] = bx;
                    s_kar[kept] = area;
                    s_ksc[kept] = myscore;
                    s_kidx[kept] = myorig;
                }
                kept++;
                live &= ~(1ull << w);   // explicit self-clear (no degenerate-IoU hang)
                live &= ~colw;
            }
        }
        if (lane == 0) s_kcount = kept;
    }
    __syncthreads();

    int kc = s_kcount;
    if (tid == 0) kcount[b] = kc;
    for (int k = tid; k < kc; k += NMS_THREADS) {
        kbox[b * MAX_OUT + k] = s_kbox[k];
        kscore[b * MAX_OUT + k] = s_ksc[k];
        kidx[b * MAX_OUT + k] = s_kidx[k];
    }
}

// ---------------- outputs: parallel write + zero-fill ----------------
__global__ void out_kernel(const float4* __restrict__ kbox,
                           const float* __restrict__ kscore,
                           const int* __restrict__ kidx,
                           const int* __restrict__ kcount,
                           const float* __restrict__ logits,
                           float* __restrict__ out) {
    int idx = blockIdx.x * blockDim.x + threadIdx.x;
    const int NB = BATCH * MAX_OUT * 5;        // 12000
    const int NS = BATCH * MAX_OUT * 2;        // 4800
    const int NL = BATCH * MAX_OUT * NCLS;     // 194400
    if (idx >= NB + NS + NL) return;

    if (idx < NB) {
        int b = idx / (MAX_OUT * 5);
        int rem = idx - b * (MAX_OUT * 5);
        int k = rem / 5, c = rem - 5 * k;
        float v = 0.f;
        if (k < kcount[b]) {
            if (c == 4) v = 1.f;
            else {
                float4 bx = kbox[b * MAX_OUT + k];
                v = (c == 0) ? bx.x : (c == 1) ? bx.y : (c == 2) ? bx.z : bx.w;
            }
        }
        out[idx] = v;
    } else if (idx < NB + NS) {
        int j = idx - NB;
        int b = j / (MAX_OUT * 2);
        int rem = j - b * (MAX_OUT * 2);
        int k = rem >> 1, c = rem & 1;
        float v = 0.f;
        if (k < kcount[b]) v = c ? 1.f : kscore[b * MAX_OUT + k];
        out[idx] = v;
    } else {
        int j = idx - NB - NS;
        int b = j / (MAX_OUT * NCLS);
        int rem = j - b * (MAX_OUT * NCLS);
        int k = rem / NCLS, c = rem - NCLS * k;
        float v = 0.f;
        if (k < kcount[b])
            v = logits[((long)b * NBOX + kidx[b * MAX_OUT + k]) * NCLS + c];
        out[idx] = v;
    }
}

extern "C" void kernel_launch(void* const* d_in, const int* in_sizes, int n_in,
                              void* d_out, int out_size, void* d_ws, size_t ws_size,
                              hipStream_t stream) {
    const float* deltas    = (const float*)d_in[0];
    const float* logits    = (const float*)d_in[1];
    const float* proposals = (const float*)d_in[2];
    float* out = (float*)d_out;

    char* ws = (char*)d_ws;
    float4* ws_boxes  = (float4*)(ws);                    // 8*2000*16 = 256000
    float*  ws_scores = (float*)(ws + 256000);            // 8*2000*4  =  64000
    float4* ws_kbox   = (float4*)(ws + 320000);           // 8*300*16  =  38400
    float*  ws_kscore = (float*)(ws + 358400);            // 8*300*4   =   9600
    int*    ws_kidx   = (int*)(ws + 368000);              // 8*300*4   =   9600
    int*    ws_kcount = (int*)(ws + 377600);              // 8*4       =     32

    prep_kernel<<<(BATCH * NBOX + 255) / 256, 256, 0, stream>>>(
        deltas, logits, proposals, ws_boxes, ws_scores);
    nms_kernel<<<BATCH, NMS_THREADS, 0, stream>>>(
        ws_boxes, ws_scores, ws_kbox, ws_kscore, ws_kidx, ws_kcount);
    int total_out = BATCH * MAX_OUT * (5 + 2 + NCLS);
    out_kernel<<<(total_out + 255) / 256, 256, 0, stream>>>(
        ws_kbox, ws_kscore, ws_kidx, ws_kcount, logits, out);
}

// Round 5
// 153.094 us; speedup vs baseline: 1.6891x; 1.6891x over previous
//
#include <hip/hip_runtime.h>

#define BATCH 8
#define NBOX 2000
#define NCLS 81
#define NPAD 2048
#define MAX_OUT 300
#define SCORE_T 0.05f
#define IOU_T 0.5f
#define MASK_WORDS 64   /* 2048 cols / 32 bits */

// ---- ws byte offsets ----
#define WS_BOXES   0          // float4[16000]           256000
#define WS_SCORES  256000     // float [16000]            64000
#define WS_SKEY    320000     // u64   [8*2048]          131072
#define WS_SBOX    451072     // float4[8*2048]          262144
#define WS_LARR    713216     // int[8]                      32
#define WS_KLIST   713248     // int[8*300]                9600
#define WS_KCOUNT  722848     // int[8]                      32
#define WS_MASK    786432     // uint[8*2048*64]        4194304  (end ~4.98 MB)

// ---------------- prep: softmax fg score/cls + box regression ----------------
__global__ void prep_kernel(const float* __restrict__ deltas,
                            const float* __restrict__ logits,
                            const float* __restrict__ proposals,
                            float4* __restrict__ boxes_out,
                            float* __restrict__ scores_out,
                            int* __restrict__ Larr) {
    int bn = blockIdx.x * blockDim.x + threadIdx.x;
    if (bn < BATCH) Larr[bn] = 0;           // zero before rank_kernel's atomicMax
    if (bn >= BATCH * NBOX) return;

    const float* l = logits + (long)bn * NCLS;

    float M = l[0];
    #pragma unroll 4
    for (int c = 1; c < NCLS; ++c) M = fmaxf(M, l[c]);

    float S = 0.0f;
    float bl = -3.0e38f; int bc = 1;
    #pragma unroll 4
    for (int c = 0; c < NCLS; ++c) {
        float v = l[c];
        S += expf(v - M);
        if (c >= 1 && v > bl) { bl = v; bc = c; }
    }
    float score = expf(bl - M) / S;

    const float* p = proposals + (long)bn * 5;
    float y1 = p[0], x1 = p[1], y2 = p[2], x2 = p[3];
    float h = y2 - y1, w = x2 - x1;
    float cy = (y2 + y1) * 0.5f, cx = (x2 + x1) * 0.5f;

    const float* d = deltas + ((long)bn * NCLS + bc) * 4;
    float d0 = d[0] * 0.1f, d1 = d[1] * 0.1f, d2 = d[2] * 0.2f, d3 = d[3] * 0.2f;

    cy = cy + d0 * h;
    cx = cx + d1 * w;
    h = h * expf(d2);
    w = w * expf(d3);

    boxes_out[bn] = make_float4(cy - h * 0.5f, cx - w * 0.5f,
                                cy + h * 0.5f, cx + w * 0.5f);
    scores_out[bn] = score;
}

// ---- rank: stable descending sort via direct rank (keys unique) + scatter ----
__global__ __launch_bounds__(256) void rank_kernel(
        const float* __restrict__ scores,
        const float4* __restrict__ boxes,
        unsigned long long* __restrict__ skey,
        float4* __restrict__ sbox,
        int* __restrict__ Larr) {
    int bid = blockIdx.x;
    int b = bid & 7, rb = bid >> 3;      // batch = bid%8 -> XCD locality
    int t = threadIdx.x;

    __shared__ unsigned long long s_key[NPAD + 16];   // +8B pad per 128 keys
    __shared__ int s_part[64][4];

    for (int c = t; c < NPAD; c += 256) {
        unsigned int bits = 0u;
        if (c < NBOX) bits = __float_as_uint(scores[b * NBOX + c]);
        s_key[c + (c >> 7)] =
            ((unsigned long long)bits << 32) |
            (unsigned long long)(0xFFFFFFFFu - (unsigned)c);
    }
    __syncthreads();

    int own = rb * 64 + (t >> 2);
    int seg = t & 3;
    unsigned long long mykey = s_key[own + (own >> 7)];
    int cnt = 0;
    int cbase = seg * 512;
    #pragma unroll 4
    for (int j = 0; j < 512; ++j) {
        int c = cbase + j;
        cnt += (s_key[c + (c >> 7)] > mykey) ? 1 : 0;
    }
    s_part[t >> 2][seg] = cnt;
    __syncthreads();

    if (t < 64) {
        int own2 = rb * 64 + t;
        unsigned long long key = s_key[own2 + (own2 >> 7)];
        int rank = s_part[t][0] + s_part[t][1] + s_part[t][2] + s_part[t][3];
        skey[b * NPAD + rank] = key;
        unsigned int orig = 0xFFFFFFFFu - (unsigned int)key;
        float4 bx = make_float4(0.f, 0.f, 0.f, 0.f);
        if (orig < NBOX) bx = boxes[b * NBOX + orig];
        sbox[b * NPAD + rank] = bx;
        float sc = __uint_as_float((unsigned int)(key >> 32));
        if (sc > SCORE_T) atomicMax(&Larr[b], rank + 1);
    }
}

// ---- mask: full pairwise suppression bitmatrix over sorted candidates ----
__global__ __launch_bounds__(256) void mask_kernel(
        const float4* __restrict__ sbox,
        unsigned int* __restrict__ mask) {
    int bid = blockIdx.x;
    int b = bid & 7, rb = bid >> 3;      // batch = bid%8 -> same XCD as walk block b
    int t = threadIdx.x;

    __shared__ float4 s_bx[NPAD + 16];   // +16B pad per 128 cols (bank stagger)

    for (int c = t; c < NPAD; c += 256)
        s_bx[c + (c >> 7)] = sbox[b * NPAD + c];
    __syncthreads();

    int r = rb * 64 + (t >> 2);
    int seg = t & 3;
    float4 rbx = s_bx[r + (r >> 7)];
    float rar = (rbx.z - rbx.x) * (rbx.w - rbx.y);
    unsigned int* out = mask + (((size_t)(b * NPAD + r)) << 6) + seg * 16;

    for (int w = 0; w < 16; ++w) {
        unsigned int bits = 0u;
        int colbase = seg * 512 + w * 32;
        #pragma unroll 8
        for (int c2 = 0; c2 < 32; ++c2) {
            int col = colbase + c2;
            float4 ob = s_bx[col + (col >> 7)];
            float oa = (ob.z - ob.x) * (ob.w - ob.y);
            float yy1 = fmaxf(rbx.x, ob.x), xx1 = fmaxf(rbx.y, ob.y);
            float yy2 = fminf(rbx.z, ob.z), xx2 = fminf(rbx.w, ob.w);
            float inter = fmaxf(yy2 - yy1, 0.f) * fmaxf(xx2 - xx1, 0.f);
            float iou = inter / (rar + oa - inter + 1e-8f);   // IEEE fdiv: bit-exact vs ref
            bits |= (iou > IOU_T) ? (1u << c2) : 0u;
        }
        out[w] = bits;
    }
}

// ---- walk: per-batch greedy over alive bitvector, 2-deep row speculation ----
__global__ __launch_bounds__(64) void walk_kernel(
        const int* __restrict__ Larr,
        const unsigned int* __restrict__ mask,
        int* __restrict__ klist,
        int* __restrict__ kcount) {
    int b = blockIdx.x;
    int lane = threadIdx.x;

    int L = Larr[b];
    int base = lane << 5;
    int nset = L - base;
    nset = nset < 0 ? 0 : (nset > 32 ? 32 : nset);
    unsigned int alive = (nset >= 32) ? 0xFFFFFFFFu
                        : ((nset <= 0) ? 0u : ((1u << nset) - 1u));

    const unsigned int* M = mask + ((size_t)b * NPAD) * MASK_WORDS;
    int* kl = klist + b * MAX_OUT;
    int kept = 0;

    while (kept < MAX_OUT) {
        unsigned long long bal = __ballot(alive != 0u);
        if (!bal) break;
        int w0 = (int)__builtin_ctzll(bal);
        unsigned int aw = (unsigned int)__builtin_amdgcn_readlane((int)alive, w0);
        int r = (w0 << 5) + (int)__builtin_ctz(aw);

        // speculative next-alive (pre-update)
        unsigned int alive2 = alive;
        if (lane == w0) alive2 &= ~(1u << (r & 31));
        unsigned long long bal2 = __ballot(alive2 != 0u);
        int r2 = -1;
        if (bal2) {
            int w1 = (int)__builtin_ctzll(bal2);
            unsigned int aw1 = (unsigned int)__builtin_amdgcn_readlane((int)alive2, w1);
            r2 = (w1 << 5) + (int)__builtin_ctz(aw1);
        }

        // issue both row loads together (latencies overlap)
        unsigned int row_r  = M[((size_t)r << 6) + lane];
        unsigned int row_r2 = (r2 >= 0) ? M[((size_t)r2 << 6) + lane] : 0u;

        // commit r
        if (lane == 0) kl[kept] = r;
        kept++;
        alive &= ~row_r;
        if (lane == (r >> 5)) alive &= ~(1u << (r & 31));

        // commit r2 if it survived r's suppression
        if (r2 >= 0 && kept < MAX_OUT) {
            unsigned int av = (unsigned int)__builtin_amdgcn_readlane((int)alive, r2 >> 5);
            if (av & (1u << (r2 & 31))) {
                if (lane == 0) kl[kept] = r2;
                kept++;
                alive &= ~row_r2;
                if (lane == (r2 >> 5)) alive &= ~(1u << (r2 & 31));
            }
        }
    }
    if (lane == 0) kcount[b] = kept;
}

// ---------------- outputs: parallel gather + zero-fill ----------------
__global__ void out_kernel(const unsigned long long* __restrict__ skey,
                           const float4* __restrict__ sbox,
                           const int* __restrict__ klist,
                           const int* __restrict__ kcount,
                           const float* __restrict__ logits,
                           float* __restrict__ out) {
    int idx = blockIdx.x * blockDim.x + threadIdx.x;
    const int NB = BATCH * MAX_OUT * 5;        // 12000
    const int NS = BATCH * MAX_OUT * 2;        // 4800
    const int NL = BATCH * MAX_OUT * NCLS;     // 194400
    if (idx >= NB + NS + NL) return;

    if (idx < NB) {
        int b = idx / (MAX_OUT * 5);
        int rem = idx - b * (MAX_OUT * 5);
        int k = rem / 5, c = rem - 5 * k;
        float v = 0.f;
        if (k < kcount[b]) {
            if (c == 4) v = 1.f;
            else {
                float4 bx = sbox[b * NPAD + klist[b * MAX_OUT + k]];
                v = (c == 0) ? bx.x : (c == 1) ? bx.y : (c == 2) ? bx.z : bx.w;
            }
        }
        out[idx] = v;
    } else if (idx < NB + NS) {
        int j = idx - NB;
        int b = j / (MAX_OUT * 2);
        int rem = j - b * (MAX_OUT * 2);
        int k = rem >> 1, c = rem & 1;
        float v = 0.f;
        if (k < kcount[b]) {
            if (c) v = 1.f;
            else {
                unsigned long long key = skey[b * NPAD + klist[b * MAX_OUT + k]];
                v = __uint_as_float((unsigned int)(key >> 32));
            }
        }
        out[idx] = v;
    } else {
        int j = idx - NB - NS;
        int b = j / (MAX_OUT * NCLS);
        int rem = j - b * (MAX_OUT * NCLS);
        int k = rem / NCLS, c = rem - NCLS * k;
        float v = 0.f;
        if (k < kcount[b]) {
            unsigned long long key = skey[b * NPAD + klist[b * MAX_OUT + k]];
            unsigned int orig = 0xFFFFFFFFu - (unsigned int)key;
            v = logits[((long)b * NBOX + orig) * NCLS + c];
        }
        out[idx] = v;
    }
}

extern "C" void kernel_launch(void* const* d_in, const int* in_sizes, int n_in,
                              void* d_out, int out_size, void* d_ws, size_t ws_size,
                              hipStream_t stream) {
    const float* deltas    = (const float*)d_in[0];
    const float* logits    = (const float*)d_in[1];
    const float* proposals = (const float*)d_in[2];
    float* out = (float*)d_out;

    char* ws = (char*)d_ws;
    float4* ws_boxes  = (float4*)(ws + WS_BOXES);
    float*  ws_scores = (float*)(ws + WS_SCORES);
    unsigned long long* ws_skey = (unsigned long long*)(ws + WS_SKEY);
    float4* ws_sbox   = (float4*)(ws + WS_SBOX);
    int*    ws_Larr   = (int*)(ws + WS_LARR);
    int*    ws_klist  = (int*)(ws + WS_KLIST);
    int*    ws_kcount = (int*)(ws + WS_KCOUNT);
    unsigned int* ws_mask = (unsigned int*)(ws + WS_MASK);

    prep_kernel<<<(BATCH * NBOX + 255) / 256, 256, 0, stream>>>(
        deltas, logits, proposals, ws_boxes, ws_scores, ws_Larr);
    rank_kernel<<<BATCH * (NPAD / 64), 256, 0, stream>>>(
        ws_scores, ws_boxes, ws_skey, ws_sbox, ws_Larr);
    mask_kernel<<<BATCH * (NPAD / 64), 256, 0, stream>>>(
        ws_sbox, ws_mask);
    walk_kernel<<<BATCH, 64, 0, stream>>>(
        ws_Larr, ws_mask, ws_klist, ws_kcount);
    int total_out = BATCH * MAX_OUT * (5 + 2 + NCLS);
    out_kernel<<<(total_out + 255) / 256, 256, 0, stream>>>(
        ws_skey, ws_sbox, ws_klist, ws_kcount, logits, out);
}